// Round 1
// baseline (485.196 us; speedup 1.0000x reference)
//
#include <hip/hip_runtime.h>
#include <cstdint>
#include <cstddef>

// Problem constants (B=4, T=2048, C=1024, H=16, S=64)
#define TT 2048
#define CC 1024
#define HH 16
#define SS 64
#define MROWS 8192  // B*T
#define KVRN 3072   // fused k|v|r width
#define NCH 32      // WKV chunks per sequence
#define LCH 64      // steps per chunk (TT/NCH)

using short8 = __attribute__((ext_vector_type(8))) short;
using f32x4  = __attribute__((ext_vector_type(4))) float;

__device__ __forceinline__ float b2f(unsigned short u) {
  union { unsigned int i; float f; } c; c.i = ((unsigned int)u) << 16; return c.f;
}
__device__ __forceinline__ unsigned short f2b(float f) {
  union { float f; unsigned int i; } c; c.f = f;
  unsigned int r = c.i + 0x7fffu + ((c.i >> 16) & 1u);  // RNE; inputs finite
  return (unsigned short)(r >> 16);
}

// async global->LDS, 16 bytes per lane (LDS dst = wave-uniform base + lane*16; global per-lane)
typedef const __attribute__((address_space(1))) unsigned int* gas_ptr;
typedef __attribute__((address_space(3))) unsigned int* las_ptr;
__device__ __forceinline__ void gl_lds16(const unsigned short* g, unsigned short* l) {
  __builtin_amdgcn_global_load_lds((gas_ptr)g, (las_ptr)l, 16, 0, 0);
}

// ---------------- fused: all weights fp32->bf16 + LN1, one launch ----------------
// blocks [0,12288): cvt; blocks [12288,20480): LN1 row (blockIdx-12288)
__global__ __launch_bounds__(256) void cvt_ln_kernel(const float* __restrict__ Wk,
                                                     const float* __restrict__ Wv,
                                                     const float* __restrict__ Wr,
                                                     const float* __restrict__ Wo,
                                                     const float* __restrict__ Wffk,
                                                     const float* __restrict__ Wffv,
                                                     unsigned short* __restrict__ dst,
                                                     const float* __restrict__ x,
                                                     const float* __restrict__ g,
                                                     const float* __restrict__ bta,
                                                     unsigned short* __restrict__ xlo) {
  const size_t M1 = 1048576;
  const int tid = threadIdx.x;
  if (blockIdx.x < 12288) {
    size_t i = ((size_t)blockIdx.x * 256 + tid) * 4;
    const float* src; size_t off;
    if      (i <  1 * M1) { src = Wk;   off = 0;      }
    else if (i <  2 * M1) { src = Wv;   off = 1 * M1; }
    else if (i <  3 * M1) { src = Wr;   off = 2 * M1; }
    else if (i <  4 * M1) { src = Wo;   off = 3 * M1; }
    else if (i <  8 * M1) { src = Wffk; off = 4 * M1; }
    else                  { src = Wffv; off = 8 * M1; }
    float4 v = *(const float4*)(src + (i - off));
    *(ushort4*)(dst + i) = make_ushort4(f2b(v.x), f2b(v.y), f2b(v.z), f2b(v.w));
    return;
  }
  const int row = blockIdx.x - 12288;
  const float* xr = x + (size_t)row * CC;
  float4 v = *(const float4*)(xr + tid * 4);
  float s  = v.x + v.y + v.z + v.w;
  float ss = v.x * v.x + v.y * v.y + v.z * v.z + v.w * v.w;
#pragma unroll
  for (int off = 32; off > 0; off >>= 1) {
    s  += __shfl_xor(s, off, 64);
    ss += __shfl_xor(ss, off, 64);
  }
  __shared__ float ls[4], lss[4];
  if ((tid & 63) == 0) { ls[tid >> 6] = s; lss[tid >> 6] = ss; }
  __syncthreads();
  s  = ls[0] + ls[1] + ls[2] + ls[3];
  ss = lss[0] + lss[1] + lss[2] + lss[3];
  const float mean = s * (1.0f / CC);
  const float var  = ss * (1.0f / CC) - mean * mean;
  const float rstd = rsqrtf(var + 1e-5f);
  float4 gv = *(const float4*)(g + tid * 4);
  float4 bv = *(const float4*)(bta + tid * 4);
  ushort4 o = make_ushort4(f2b((v.x - mean) * rstd * gv.x + bv.x),
                           f2b((v.y - mean) * rstd * gv.y + bv.y),
                           f2b((v.z - mean) * rstd * gv.z + bv.z),
                           f2b((v.w - mean) * rstd * gv.w + bv.w));
  *(ushort4*)(xlo + (size_t)row * CC + tid * 4) = o;
}

// ---------------- LayerNorm (fp32 in, bf16 out) + fp32 passthrough seed ----------------
// outc gets a copy of the fp32 input row (seeds `out` with x2 for the atomic split-K GEMM)
__global__ __launch_bounds__(256) void ln_kernel(const float* __restrict__ x,
                                                 const float* __restrict__ g,
                                                 const float* __restrict__ bta,
                                                 unsigned short* __restrict__ out,
                                                 float* __restrict__ outc) {
  const int row = blockIdx.x;
  const int tid = threadIdx.x;
  const float* xr = x + (size_t)row * CC;
  float4 v = *(const float4*)(xr + tid * 4);
  *(float4*)(outc + (size_t)row * CC + tid * 4) = v;  // seed out = x2
  float s  = v.x + v.y + v.z + v.w;
  float ss = v.x * v.x + v.y * v.y + v.z * v.z + v.w * v.w;
#pragma unroll
  for (int off = 32; off > 0; off >>= 1) {
    s  += __shfl_xor(s, off, 64);
    ss += __shfl_xor(ss, off, 64);
  }
  __shared__ float ls[4], lss[4];
  if ((tid & 63) == 0) { ls[tid >> 6] = s; lss[tid >> 6] = ss; }
  __syncthreads();
  s  = ls[0] + ls[1] + ls[2] + ls[3];
  ss = lss[0] + lss[1] + lss[2] + lss[3];
  const float mean = s * (1.0f / CC);
  const float var  = ss * (1.0f / CC) - mean * mean;
  const float rstd = rsqrtf(var + 1e-5f);
  float4 gv = *(const float4*)(g + tid * 4);
  float4 bv = *(const float4*)(bta + tid * 4);
  ushort4 o = make_ushort4(f2b((v.x - mean) * rstd * gv.x + bv.x),
                           f2b((v.y - mean) * rstd * gv.y + bv.y),
                           f2b((v.z - mean) * rstd * gv.z + bv.z),
                           f2b((v.w - mean) * rstd * gv.w + bv.w));
  *(ushort4*)(out + (size_t)row * CC + tid * 4) = o;
}

// ---------------- WKV hierarchical scan, 2 kernels ----------------
__global__ __launch_bounds__(64) void wkv_local(const unsigned short* __restrict__ kvr,
                                                const float* __restrict__ td,
                                                const float* __restrict__ tfp,
                                                float* __restrict__ scratch) {
  const int blk = blockIdx.x;
  const int bh = blk >> 5, c = blk & (NCH - 1);
  const int b = bh >> 4, h = bh & 15;
  const int s = threadIdx.x;
  const int ch = h * SS + s;
  const float e = __expf(td[ch]);
  const float d = __expf(-e);
  const float tfir = __expf(tfp[ch]);
  size_t idx = ((size_t)b * TT + (size_t)c * LCH) * KVRN + ch;
  float num = 0.f, den = 0.f;
  for (int i = 0; i < LCH; ++i) {
    float w = __expf(fminf(b2f(kvr[idx]), 30.f));
    if (c == 0 && i == 0) w *= tfir;  // time_first seeding at t==0
    float vv = b2f(kvr[idx + 1024]);
    num = d * num + w * vv;
    den = d * den + w;
    idx += KVRN;
  }
  float* o = scratch + ((size_t)bh * NCH + c) * 128;
  o[s] = num; o[64 + s] = den;
}

__global__ __launch_bounds__(64) void wkv_emit(const unsigned short* __restrict__ kvr,
                                               const float* __restrict__ td,
                                               const float* __restrict__ tfp,
                                               const float* __restrict__ scratch,
                                               unsigned short* __restrict__ rwkv) {
  const int blk = blockIdx.x;
  const int bh = blk >> 5, c = blk & (NCH - 1);
  const int b = bh >> 4, h = bh & 15;
  const int s = threadIdx.x;
  const int ch = h * SS + s;
  const float e = __expf(td[ch]);
  const float d = __expf(-e);
  const float Dc = __expf(-e * (float)LCH);
  const float tfir = __expf(tfp[ch]);
  float num = 0.f, den = 0.f;
  const float* sc = scratch + (size_t)bh * NCH * 128;
  for (int cc = 0; cc < c; ++cc) {
    num = Dc * num + sc[cc * 128 + s];
    den = Dc * den + sc[cc * 128 + 64 + s];
  }
  size_t idx = ((size_t)b * TT + (size_t)c * LCH) * KVRN + ch;
  size_t odx = ((size_t)b * TT + (size_t)c * LCH) * CC + ch;
  for (int i = 0; i < LCH; ++i) {
    float w = __expf(fminf(b2f(kvr[idx]), 30.f));
    if (c == 0 && i == 0) w *= tfir;
    float vv = b2f(kvr[idx + 1024]);
    num = d * num + w * vv;
    den = d * den + w;
    float o = num / (den + 1e-6f);
    float rr = b2f(kvr[idx + 2048]);
    float sg = 1.0f / (1.0f + __expf(-rr));
    rwkv[odx] = f2b(sg * o);
    idx += KVRN;
    odx += CC;
  }
}

// ---------------- bf16 MFMA GEMM, 256x256 tile, 8-phase counted-vmcnt schedule ----------
// C[M,N] = A[M,K_loop slice] @ Bw[N,K]^T (+res / relu^2 / atomic variants)
// 8 waves (2M x 4N), per-wave 128x64 output, BK=64 split into kk-halves of 32.
// LDS: As/Bs[2 buf][2 kk][256 rows][32 k] = 128 KiB total, 1 block/CU.
// Swizzle: logical k-group q (8 bf16) of row r lives at slot q^(r&3) -> ds_read_b128
//   across 64 lanes lands 8 lanes per 16B bank-slot class = conflict-free (balanced).
//   Applied by pre-swizzling the global source address; LDS stays linear for gl_lds.
// Schedule per K-tile = 4 phases, each:
//   { ds_read subtile (8 or 4 x b128) ; stage 1 half-tile (2 x global_load_lds) ;
//     [vmcnt(8) at P1,P3] ; s_barrier ; lgkmcnt(0) ; setprio(1) 16xMFMA setprio(0) ; s_barrier }
// vmcnt is NEVER drained to 0 in the loop (T4): stages are issued unconditionally with the
// K-offset clamped to the last tile, so the outstanding-load count is exact in all tiles and
// vmcnt(8) always certifies precisely the 4 oldest in-flight half-tiles.
// Race-freedom: a kk-half region is staged only in the phase AFTER the barrier that follows
// its last reader's lgkmcnt(0) (reads complete pre-MFMA, stage issued post-bar2) -> no window.
// EP=0 bf16 store; EP=1 relu^2 bf16; EP=2 fp32 + res; EP=3 fp32 unsafeAtomicAdd (split-K)
#define GBAR do { __builtin_amdgcn_sched_barrier(0); __builtin_amdgcn_s_barrier(); \
                  __builtin_amdgcn_sched_barrier(0); } while (0)
#define WAIT_LGKM0 do { __builtin_amdgcn_s_waitcnt(0xC07F); \
                        __builtin_amdgcn_sched_barrier(0); } while (0)
#define WAIT_VM8   do { __builtin_amdgcn_sched_barrier(0); \
                        __builtin_amdgcn_s_waitcnt(0x0F78); \
                        __builtin_amdgcn_sched_barrier(0); } while (0)

template <int EP>
__global__ __launch_bounds__(512, 2) void gemm256(const unsigned short* __restrict__ A,
                                                  const unsigned short* __restrict__ Bw,
                                                  void* __restrict__ outv,
                                                  const float* __restrict__ res,
                                                  int N, int Kfull, int Kloop) {
  __shared__ __align__(16) unsigned short As[2][2][256][32];
  __shared__ __align__(16) unsigned short Bs[2][2][256][32];
  const int tid = threadIdx.x;

  // grid decode: groups of 16 bm-tiles sweep all bn for L2 reuse of B panels
  const int nbn = N >> 8;
  const int per_grp = nbn << 4;
  const int bid = blockIdx.x;
  const int grp = bid / per_grp;
  const int rem = bid - grp * per_grp;
  const int bm = (grp << 4) + (rem & 15);
  const int bn = rem >> 4;
  const int koffb = blockIdx.y * Kloop;  // split-K slice offset
  const int nt = Kloop >> 6;

  // staging addresses: half-tile = one kk-half of A or B (256 rows x 32 k = 16 KiB);
  // thread stages 16B chunks tid (rows 0..127) and tid+512 (rows 128..255).
  const int r0  = tid >> 2;                           // row within lower half
  const int qsl = ((tid & 3) ^ (r0 & 3)) << 3;        // pre-swizzled source k-group
  const unsigned short* gA0 = A  + (size_t)(bm * 256 + r0) * Kfull + koffb + qsl;
  const unsigned short* gA1 = gA0 + (size_t)128 * Kfull;
  const unsigned short* gB0 = Bw + (size_t)(bn * 256 + r0) * Kfull + koffb + qsl;
  const unsigned short* gB1 = gB0 + (size_t)128 * Kfull;
  const int ldsoff = tid * 8;

  auto stA = [&](int bb, int kk, int ko) {
    unsigned short* d = &As[bb][kk][0][0];
    gl_lds16(gA0 + ko, d + ldsoff);
    gl_lds16(gA1 + ko, d + ldsoff + 4096);
  };
  auto stB = [&](int bb, int kk, int ko) {
    unsigned short* d = &Bs[bb][kk][0][0];
    gl_lds16(gB0 + ko, d + ldsoff);
    gl_lds16(gB1 + ko, d + ldsoff + 4096);
  };

  // fragment read bases (swizzled): element offset = row*32 + (q ^ (row&3))*8
  const int lane = tid & 63, w = tid >> 6;
  const int wr = w >> 2, wn = w & 3;                  // 2M x 4N waves
  const int r16 = lane & 15, q = lane >> 4;
  const int qx = (q ^ (r16 & 3)) << 3;
  const unsigned short* fA = &As[0][0][0][0] + (wr * 128 + r16) * 32 + qx;
  const unsigned short* fB = &Bs[0][0][0][0] + (wn * 64  + r16) * 32 + qx;

  f32x4 acc[8][4] = {};
  short8 af[4], bf_[4];

  // prologue: A0(0) B0(0) A1(0) B1(0) A0(1) B0(1)  (12 loads); vmcnt(8) -> tile0 kk0 landed
  stA(0, 0, 0);  stB(0, 0, 0);
  stA(0, 1, 32); stB(0, 1, 32);
  stA(1, 0, 64); stB(1, 0, 64);
  WAIT_VM8;
  GBAR;

  int b = 0;
  for (int t = 0; t < nt; ++t, b ^= 1) {
    const unsigned short* fAb = fA + b * 16384;
    const unsigned short* fBb = fB + b * 16384;
    const int t1 = (t + 1 < nt) ? t + 1 : nt - 1;    // clamped: keeps vmcnt count exact
    const int t2 = (t + 2 < nt) ? t + 2 : nt - 1;    // (dead-region restage, data unread)
    const int ko1 = (t1 << 6) + 32;                  // kk1 half of tile t+1
    const int ko2 = (t2 << 6);                       // kk0 half of tile t+2

    // ---- P0: A kk0 m0-3 + B kk0 n0-3 ; stage A1(t+1) ----
#pragma unroll
    for (int i = 0; i < 4; ++i) af[i]  = *(const short8*)(fAb + i * 512);
#pragma unroll
    for (int i = 0; i < 4; ++i) bf_[i] = *(const short8*)(fBb + i * 512);
    stA(b ^ 1, 1, ko1);
    GBAR;
    WAIT_LGKM0;
    __builtin_amdgcn_s_setprio(1);
#pragma unroll
    for (int mi = 0; mi < 4; ++mi)
#pragma unroll
      for (int ni = 0; ni < 4; ++ni)
        acc[mi][ni] = __builtin_amdgcn_mfma_f32_16x16x32_bf16(af[mi], bf_[ni], acc[mi][ni], 0, 0, 0);
    __builtin_amdgcn_s_setprio(0);
    GBAR;

    // ---- P1: A kk0 m4-7 ; stage B1(t+1) ; vmcnt(8) certifies A1(t),B1(t) ----
#pragma unroll
    for (int i = 0; i < 4; ++i) af[i] = *(const short8*)(fAb + (4 + i) * 512);
    stB(b ^ 1, 1, ko1);
    WAIT_VM8;
    GBAR;
    WAIT_LGKM0;
    __builtin_amdgcn_s_setprio(1);
#pragma unroll
    for (int mi = 0; mi < 4; ++mi)
#pragma unroll
      for (int ni = 0; ni < 4; ++ni)
        acc[4 + mi][ni] = __builtin_amdgcn_mfma_f32_16x16x32_bf16(af[mi], bf_[ni], acc[4 + mi][ni], 0, 0, 0);
    __builtin_amdgcn_s_setprio(0);
    GBAR;

    // ---- P2: A kk1 m0-3 + B kk1 n0-3 ; stage A0(t+2) (kk0 of this buf, released @P1) ----
#pragma unroll
    for (int i = 0; i < 4; ++i) af[i]  = *(const short8*)(fAb + 8192 + i * 512);
#pragma unroll
    for (int i = 0; i < 4; ++i) bf_[i] = *(const short8*)(fBb + 8192 + i * 512);
    stA(b, 0, ko2);
    GBAR;
    WAIT_LGKM0;
    __builtin_amdgcn_s_setprio(1);
#pragma unroll
    for (int mi = 0; mi < 4; ++mi)
#pragma unroll
      for (int ni = 0; ni < 4; ++ni)
        acc[mi][ni] = __builtin_amdgcn_mfma_f32_16x16x32_bf16(af[mi], bf_[ni], acc[mi][ni], 0, 0, 0);
    __builtin_amdgcn_s_setprio(0);
    GBAR;

    // ---- P3: A kk1 m4-7 ; stage B0(t+2) ; vmcnt(8) certifies A0(t+1),B0(t+1) ----
#pragma unroll
    for (int i = 0; i < 4; ++i) af[i] = *(const short8*)(fAb + 8192 + (4 + i) * 512);
    stB(b, 0, ko2);
    WAIT_VM8;
    GBAR;
    WAIT_LGKM0;
    __builtin_amdgcn_s_setprio(1);
#pragma unroll
    for (int mi = 0; mi < 4; ++mi)
#pragma unroll
      for (int ni = 0; ni < 4; ++ni)
        acc[4 + mi][ni] = __builtin_amdgcn_mfma_f32_16x16x32_bf16(af[mi], bf_[ni], acc[4 + mi][ni], 0, 0, 0);
    __builtin_amdgcn_s_setprio(0);
    GBAR;
  }

  // drain leftover prefetches (land into dead LDS regions), then epilogue
  __builtin_amdgcn_s_waitcnt(0x0070);

  // D[m = q*4+reg][n = lane&15] per 16x16 fragment
#pragma unroll
  for (int mi = 0; mi < 8; ++mi) {
#pragma unroll
    for (int r = 0; r < 4; ++r) {
      const int grow = bm * 256 + wr * 128 + mi * 16 + q * 4 + r;
#pragma unroll
      for (int ni = 0; ni < 4; ++ni) {
        const int gcol = bn * 256 + wn * 64 + ni * 16 + r16;
        const size_t idx = (size_t)grow * N + gcol;
        float vv = acc[mi][ni][r];
        if (EP == 2) {
          ((float*)outv)[idx] = res[idx] + vv;
        } else if (EP == 3) {
          unsafeAtomicAdd((float*)outv + idx, vv);
        } else {
          if (EP == 1) { vv = fmaxf(vv, 0.0f); vv = vv * vv; }
          ((unsigned short*)outv)[idx] = f2b(vv);
        }
      }
    }
  }
}

extern "C" void kernel_launch(void* const* d_in, const int* in_sizes, int n_in,
                              void* d_out, int out_size, void* d_ws, size_t ws_size,
                              hipStream_t stream) {
  const float* x    = (const float*)d_in[0];
  const float* td   = (const float*)d_in[1];
  const float* tf   = (const float*)d_in[2];
  const float* Wk   = (const float*)d_in[3];
  const float* Wv   = (const float*)d_in[4];
  const float* Wr   = (const float*)d_in[5];
  const float* Wo   = (const float*)d_in[6];
  const float* Wffk = (const float*)d_in[7];
  const float* Wffv = (const float*)d_in[8];
  const float* g1   = (const float*)d_in[9];
  const float* b1   = (const float*)d_in[10];
  const float* g2   = (const float*)d_in[11];
  const float* b2   = (const float*)d_in[12];
  float* out = (float*)d_out;

  char* ws = (char*)d_ws;
  const size_t MB = 1024ull * 1024ull;
  unsigned short* WB    = (unsigned short*)ws;              // 24 MB contiguous bf16 weights
  unsigned short* WkvrB = WB;                               // [3072,1024]
  unsigned short* WoB   = WB + 3 * 1048576;                 // [1024,1024]
  unsigned short* WfkB  = WB + 4 * 1048576;                 // [4096,1024]
  unsigned short* WfvB  = WB + 8 * 1048576;                 // [1024,4096]
  unsigned short* xl    = (unsigned short*)(ws + 24 * MB);  // 16 MB (reused as rwkv)
  unsigned short* kvr   = (unsigned short*)(ws + 40 * MB);  // 48 MB [8192,3072] (reused as xl2)
  float*          x2    = (float*)(ws + 88 * MB);           // 32 MB
  unsigned short* hb    = (unsigned short*)(ws + 120 * MB); // 64 MB
  float*          wkvS  = (float*)(ws + 184 * MB);          // 1 MB scan scratch -> total 185 MB
  unsigned short* rwkv  = xl;   // xl dead after kvr GEMM
  unsigned short* xl2   = kvr;  // kvr dead after wkv_emit

  // weights -> bf16 + LN1, fused single launch
  cvt_ln_kernel<<<12288 + MROWS, 256, 0, stream>>>(Wk, Wv, Wr, Wo, Wffk, Wffv, WB,
                                                   x, g1, b1, xl);

  // fused k|v|r GEMM: kvr[M,3072] = xl @ WkvrB^T   (384 blocks, 256^2 tiles)
  gemm256<0><<<dim3((KVRN / 256) * (MROWS / 256), 1), 512, 0, stream>>>(
      xl, WkvrB, kvr, nullptr, KVRN, 1024, 1024);

  // WKV hierarchical scan + sigmoid(r) fuse
  wkv_local<<<64 * NCH, 64, 0, stream>>>(kvr, td, tf, wkvS);
  wkv_emit<<<64 * NCH, 64, 0, stream>>>(kvr, td, tf, wkvS, rwkv);

  // x2 = x + rwkv @ Wo^T   (128 blocks)
  gemm256<2><<<dim3((CC / 256) * (MROWS / 256), 1), 512, 0, stream>>>(
      rwkv, WoB, x2, x, CC, 1024, 1024);

  // LN2 (+ seed out = x2 for the atomic split-K epilogue below)
  ln_kernel<<<MROWS, 256, 0, stream>>>(x2, g2, b2, xl2, out);

  // h = relu(xl2 @ Wffk^T)^2   (512 blocks)
  gemm256<1><<<dim3((4096 / 256) * (MROWS / 256), 1), 512, 0, stream>>>(
      xl2, WfkB, hb, nullptr, 4096, 1024, 1024);

  // out += h @ Wffv^T   (split-K x2: 2x128 blocks, K=2048 each, fp32 atomic add)
  gemm256<3><<<dim3((CC / 256) * (MROWS / 256), 2), 512, 0, stream>>>(
      hb, WfvB, out, nullptr, CC, 4096, 2048);
}

// Round 2
// 484.804 us; speedup vs baseline: 1.0008x; 1.0008x over previous
//
#include <hip/hip_runtime.h>
#include <cstdint>
#include <cstddef>

// Problem constants (B=4, T=2048, C=1024, H=16, S=64)
#define TT 2048
#define CC 1024
#define HH 16
#define SS 64
#define MROWS 8192  // B*T
#define KVRN 3072   // fused k|v|r width
#define NCH 32      // WKV chunks per sequence
#define LCH 64      // steps per chunk (TT/NCH)

using short8 = __attribute__((ext_vector_type(8))) short;
using f32x4  = __attribute__((ext_vector_type(4))) float;

__device__ __forceinline__ float b2f(unsigned short u) {
  union { unsigned int i; float f; } c; c.i = ((unsigned int)u) << 16; return c.f;
}
__device__ __forceinline__ unsigned short f2b(float f) {
  union { float f; unsigned int i; } c; c.f = f;
  unsigned int r = c.i + 0x7fffu + ((c.i >> 16) & 1u);  // RNE; inputs finite
  return (unsigned short)(r >> 16);
}

// async global->LDS, 16 bytes per lane (LDS dst = wave-uniform base + lane*16; global per-lane)
typedef const __attribute__((address_space(1))) unsigned int* gas_ptr;
typedef __attribute__((address_space(3))) unsigned int* las_ptr;
__device__ __forceinline__ void gl_lds16(const unsigned short* g, unsigned short* l) {
  __builtin_amdgcn_global_load_lds((gas_ptr)g, (las_ptr)l, 16, 0, 0);
}

// ---------------- fused: all weights fp32->bf16 + LN1 + x2:=x seed, one launch ----------
// blocks [0,12288): cvt; blocks [12288,20480): LN1 row (blockIdx-12288)
__global__ __launch_bounds__(256) void cvt_ln_kernel(const float* __restrict__ Wk,
                                                     const float* __restrict__ Wv,
                                                     const float* __restrict__ Wr,
                                                     const float* __restrict__ Wo,
                                                     const float* __restrict__ Wffk,
                                                     const float* __restrict__ Wffv,
                                                     unsigned short* __restrict__ dst,
                                                     const float* __restrict__ x,
                                                     const float* __restrict__ g,
                                                     const float* __restrict__ bta,
                                                     unsigned short* __restrict__ xlo,
                                                     float* __restrict__ x2o) {
  const size_t M1 = 1048576;
  const int tid = threadIdx.x;
  if (blockIdx.x < 12288) {
    size_t i = ((size_t)blockIdx.x * 256 + tid) * 4;
    const float* src; size_t off;
    if      (i <  1 * M1) { src = Wk;   off = 0;      }
    else if (i <  2 * M1) { src = Wv;   off = 1 * M1; }
    else if (i <  3 * M1) { src = Wr;   off = 2 * M1; }
    else if (i <  4 * M1) { src = Wo;   off = 3 * M1; }
    else if (i <  8 * M1) { src = Wffk; off = 4 * M1; }
    else                  { src = Wffv; off = 8 * M1; }
    float4 v = *(const float4*)(src + (i - off));
    *(ushort4*)(dst + i) = make_ushort4(f2b(v.x), f2b(v.y), f2b(v.z), f2b(v.w));
    return;
  }
  const int row = blockIdx.x - 12288;
  const float* xr = x + (size_t)row * CC;
  float4 v = *(const float4*)(xr + tid * 4);
  *(float4*)(x2o + (size_t)row * CC + tid * 4) = v;  // seed x2 = x (Wo GEMM atomic-adds)
  float s  = v.x + v.y + v.z + v.w;
  float ss = v.x * v.x + v.y * v.y + v.z * v.z + v.w * v.w;
#pragma unroll
  for (int off = 32; off > 0; off >>= 1) {
    s  += __shfl_xor(s, off, 64);
    ss += __shfl_xor(ss, off, 64);
  }
  __shared__ float ls[4], lss[4];
  if ((tid & 63) == 0) { ls[tid >> 6] = s; lss[tid >> 6] = ss; }
  __syncthreads();
  s  = ls[0] + ls[1] + ls[2] + ls[3];
  ss = lss[0] + lss[1] + lss[2] + lss[3];
  const float mean = s * (1.0f / CC);
  const float var  = ss * (1.0f / CC) - mean * mean;
  const float rstd = rsqrtf(var + 1e-5f);
  float4 gv = *(const float4*)(g + tid * 4);
  float4 bv = *(const float4*)(bta + tid * 4);
  ushort4 o = make_ushort4(f2b((v.x - mean) * rstd * gv.x + bv.x),
                           f2b((v.y - mean) * rstd * gv.y + bv.y),
                           f2b((v.z - mean) * rstd * gv.z + bv.z),
                           f2b((v.w - mean) * rstd * gv.w + bv.w));
  *(ushort4*)(xlo + (size_t)row * CC + tid * 4) = o;
}

// ---------------- LayerNorm (fp32 in, bf16 out) + fp32 passthrough seed ----------------
// outc gets a copy of the fp32 input row (seeds `out` with x2 for the atomic split-K GEMM)
__global__ __launch_bounds__(256) void ln_kernel(const float* __restrict__ x,
                                                 const float* __restrict__ g,
                                                 const float* __restrict__ bta,
                                                 unsigned short* __restrict__ out,
                                                 float* __restrict__ outc) {
  const int row = blockIdx.x;
  const int tid = threadIdx.x;
  const float* xr = x + (size_t)row * CC;
  float4 v = *(const float4*)(xr + tid * 4);
  *(float4*)(outc + (size_t)row * CC + tid * 4) = v;  // seed out = x2
  float s  = v.x + v.y + v.z + v.w;
  float ss = v.x * v.x + v.y * v.y + v.z * v.z + v.w * v.w;
#pragma unroll
  for (int off = 32; off > 0; off >>= 1) {
    s  += __shfl_xor(s, off, 64);
    ss += __shfl_xor(ss, off, 64);
  }
  __shared__ float ls[4], lss[4];
  if ((tid & 63) == 0) { ls[tid >> 6] = s; lss[tid >> 6] = ss; }
  __syncthreads();
  s  = ls[0] + ls[1] + ls[2] + ls[3];
  ss = lss[0] + lss[1] + lss[2] + lss[3];
  const float mean = s * (1.0f / CC);
  const float var  = ss * (1.0f / CC) - mean * mean;
  const float rstd = rsqrtf(var + 1e-5f);
  float4 gv = *(const float4*)(g + tid * 4);
  float4 bv = *(const float4*)(bta + tid * 4);
  ushort4 o = make_ushort4(f2b((v.x - mean) * rstd * gv.x + bv.x),
                           f2b((v.y - mean) * rstd * gv.y + bv.y),
                           f2b((v.z - mean) * rstd * gv.z + bv.z),
                           f2b((v.w - mean) * rstd * gv.w + bv.w));
  *(ushort4*)(out + (size_t)row * CC + tid * 4) = o;
}

// ---------------- WKV hierarchical scan, 2 kernels ----------------
__global__ __launch_bounds__(64) void wkv_local(const unsigned short* __restrict__ kvr,
                                                const float* __restrict__ td,
                                                const float* __restrict__ tfp,
                                                float* __restrict__ scratch) {
  const int blk = blockIdx.x;
  const int bh = blk >> 5, c = blk & (NCH - 1);
  const int b = bh >> 4, h = bh & 15;
  const int s = threadIdx.x;
  const int ch = h * SS + s;
  const float e = __expf(td[ch]);
  const float d = __expf(-e);
  const float tfir = __expf(tfp[ch]);
  size_t idx = ((size_t)b * TT + (size_t)c * LCH) * KVRN + ch;
  float num = 0.f, den = 0.f;
  for (int i = 0; i < LCH; ++i) {
    float w = __expf(fminf(b2f(kvr[idx]), 30.f));
    if (c == 0 && i == 0) w *= tfir;  // time_first seeding at t==0
    float vv = b2f(kvr[idx + 1024]);
    num = d * num + w * vv;
    den = d * den + w;
    idx += KVRN;
  }
  float* o = scratch + ((size_t)bh * NCH + c) * 128;
  o[s] = num; o[64 + s] = den;
}

__global__ __launch_bounds__(64) void wkv_emit(const unsigned short* __restrict__ kvr,
                                               const float* __restrict__ td,
                                               const float* __restrict__ tfp,
                                               const float* __restrict__ scratch,
                                               unsigned short* __restrict__ rwkv) {
  const int blk = blockIdx.x;
  const int bh = blk >> 5, c = blk & (NCH - 1);
  const int b = bh >> 4, h = bh & 15;
  const int s = threadIdx.x;
  const int ch = h * SS + s;
  const float e = __expf(td[ch]);
  const float d = __expf(-e);
  const float Dc = __expf(-e * (float)LCH);
  const float tfir = __expf(tfp[ch]);
  float num = 0.f, den = 0.f;
  const float* sc = scratch + (size_t)bh * NCH * 128;
  for (int cc = 0; cc < c; ++cc) {
    num = Dc * num + sc[cc * 128 + s];
    den = Dc * den + sc[cc * 128 + 64 + s];
  }
  size_t idx = ((size_t)b * TT + (size_t)c * LCH) * KVRN + ch;
  size_t odx = ((size_t)b * TT + (size_t)c * LCH) * CC + ch;
  for (int i = 0; i < LCH; ++i) {
    float w = __expf(fminf(b2f(kvr[idx]), 30.f));
    if (c == 0 && i == 0) w *= tfir;
    float vv = b2f(kvr[idx + 1024]);
    num = d * num + w * vv;
    den = d * den + w;
    float o = num / (den + 1e-6f);
    float rr = b2f(kvr[idx + 2048]);
    float sg = 1.0f / (1.0f + __expf(-rr));
    rwkv[odx] = f2b(sg * o);
    idx += KVRN;
    odx += CC;
  }
}

// ---------------- bf16 MFMA GEMM, 256x256 tile, gemm_bt-style pipelined schedule -------
// C[M,N] = A[M,Kslice] @ Bw[N,K]^T. 8 waves (2M x 4N), per-wave 128x64 output.
// BK=32, FOUR LDS buffers (As/Bs[4][256][32] = 128 KiB), prefetch distance 3 tiles.
// Swizzle (== proven gemm_bt, 0 conflicts): logical k-group q of row r stored at slot
//   q ^ ((r>>1)&3); applied by pre-swizzling the global source (LDS stays linear for
//   gl_lds) and XORing the fragment-read slot. Row stride 64B alternates bank halves by
//   row parity; (r>>1)&3 spreads 8 same-parity rows over 4 slot classes -> 2-way = free.
// Per K-step: { 12 ds_read_b128 ; stage tile t+3 (4 gl_lds) ; vmcnt(8) ; s_barrier ;
//               lgkmcnt(0) ; setprio(1) 32xMFMA setprio(0) }  -- ONE barrier per K-step.
// Invariant: enter phase with 8 loads in flight {t+1,t+2}; stage -> 12; vmcnt(8) retires
// tile t+1's 4 chunks. Phase t's ds_reads (issued pre-barrier) read tile t, certified by
// phase t-1's vmcnt(8)+barrier. Buffer WAR (stage t+3 overwrites tile t-1) separated by
// phase t-1's barrier + HBM latency >> LDS-read pipeline depth (same margin as gemm_bt).
// Tail stages are clamped re-fetches of tile nt-1 into dead buffers: vmcnt stays exact.
// EP=0 bf16 store; EP=1 relu^2 bf16; EP=2 fp32 + res; EP=3 fp32 unsafeAtomicAdd (split-K)
#define GBAR do { __builtin_amdgcn_sched_barrier(0); asm volatile("s_barrier"); \
                  __builtin_amdgcn_sched_barrier(0); } while (0)
#define WAIT_LGKM0 do { __builtin_amdgcn_s_waitcnt(0xC07F); \
                        __builtin_amdgcn_sched_barrier(0); } while (0)
#define WAIT_VM8   do { __builtin_amdgcn_sched_barrier(0); \
                        __builtin_amdgcn_s_waitcnt(0x0F78); \
                        __builtin_amdgcn_sched_barrier(0); } while (0)

template <int EP>
__global__ __launch_bounds__(512, 2) void gemm256(const unsigned short* __restrict__ A,
                                                  const unsigned short* __restrict__ Bw,
                                                  void* __restrict__ outv,
                                                  const float* __restrict__ res,
                                                  int N, int Kfull, int Kloop) {
  __shared__ __align__(16) unsigned short As[4][256][32];
  __shared__ __align__(16) unsigned short Bs[4][256][32];
  const int tid = threadIdx.x;

  // grid decode: groups of 16 bm-tiles sweep all bn for L2 reuse of B panels
  const int nbn = N >> 8;
  const int per_grp = nbn << 4;
  const int bid = blockIdx.x;
  const int grp = bid / per_grp;
  const int rem = bid - grp * per_grp;
  const int bm = (grp << 4) + (rem & 15);
  const int bn = rem >> 4;
  const int koffb = blockIdx.y * Kloop;  // split-K slice offset
  const int nt = Kloop >> 5;             // >= 16 for all launches here

  // staging: per buffer, A = 512 chunks of 16B; thread owns chunks tid and tid+512.
  // chunk c: row=c>>2, slot=c&3, source k-group = slot ^ ((row>>1)&3) = (tid&3)^((tid>>3)&3)
  // (identical for the +512 chunk since row+128 keeps (row>>1)&3).
  const int r0  = tid >> 2;
  const int qsl = ((tid & 3) ^ ((tid >> 3) & 3)) << 3;
  const unsigned short* gA0 = A  + (size_t)(bm * 256 + r0) * Kfull + koffb + qsl;
  const unsigned short* gA1 = gA0 + (size_t)128 * Kfull;
  const unsigned short* gB0 = Bw + (size_t)(bn * 256 + r0) * Kfull + koffb + qsl;
  const unsigned short* gB1 = gB0 + (size_t)128 * Kfull;
  const int ldsoff = tid * 8;

  auto stage = [&](int bb, int ko) {
    unsigned short* da = &As[bb][0][0];
    unsigned short* db = &Bs[bb][0][0];
    gl_lds16(gA0 + ko, da + ldsoff);
    gl_lds16(gA1 + ko, da + ldsoff + 4096);
    gl_lds16(gB0 + ko, db + ldsoff);
    gl_lds16(gB1 + ko, db + ldsoff + 4096);
  };

  // fragment read bases: element offset = row*32 + (q ^ ((row>>1)&3))*8; all fragment
  // row-bases are multiples of 16 so (r16>>1)&3 is the full swizzle term.
  const int lane = tid & 63, w = tid >> 6;
  const int wr = w >> 2, wn = w & 3;                  // 2M x 4N waves
  const int r16 = lane & 15, q = lane >> 4;
  const int qx = (q ^ ((r16 >> 1) & 3)) << 3;
  const unsigned short* fA = &As[0][0][0] + (wr * 128 + r16) * 32 + qx;
  const unsigned short* fB = &Bs[0][0][0] + (wn * 64  + r16) * 32 + qx;

  f32x4 acc[8][4] = {};
  short8 af[8], bf_[4];

  // prologue: tiles 0,1,2 -> buffers 0,1,2 (12 loads); vmcnt(8) -> own tile0 chunks
  // landed; barrier -> ALL waves' tile0 chunks landed before any phase-0 ds_read.
  stage(0, 0);
  stage(1, 32);
  stage(2, 64);
  WAIT_VM8;
  GBAR;
  WAIT_LGKM0;  // no-op (no lgkm outstanding), keeps scheduler honest

  for (int t = 0; t < nt; ++t) {
    const unsigned short* fAb = fA + (t & 3) * 8192;
    const unsigned short* fBb = fB + (t & 3) * 8192;
#pragma unroll
    for (int i = 0; i < 8; ++i) af[i]  = *(const short8*)(fAb + i * 512);
#pragma unroll
    for (int i = 0; i < 4; ++i) bf_[i] = *(const short8*)(fBb + i * 512);
    const int t3 = (t + 3 < nt) ? t + 3 : nt - 1;    // clamped: keeps vmcnt exact
    stage((t + 3) & 3, t3 << 5);
    WAIT_VM8;      // retires tile t+1's 4 chunks (own); 8 stay in flight
    GBAR;          // all waves ready: tile t+1 fully in LDS for next phase's reads
    WAIT_LGKM0;    // this phase's 12 ds_reads complete
    __builtin_amdgcn_s_setprio(1);
#pragma unroll
    for (int mi = 0; mi < 8; ++mi)
#pragma unroll
      for (int ni = 0; ni < 4; ++ni)
        acc[mi][ni] = __builtin_amdgcn_mfma_f32_16x16x32_bf16(af[mi], bf_[ni], acc[mi][ni], 0, 0, 0);
    __builtin_amdgcn_s_setprio(0);
  }

  // drain leftover prefetches (dead-buffer restages), then epilogue
  __builtin_amdgcn_s_waitcnt(0x0070);

  // D[m = q*4+reg][n = lane&15] per 16x16 fragment
#pragma unroll
  for (int mi = 0; mi < 8; ++mi) {
#pragma unroll
    for (int r = 0; r < 4; ++r) {
      const int grow = bm * 256 + wr * 128 + mi * 16 + q * 4 + r;
#pragma unroll
      for (int ni = 0; ni < 4; ++ni) {
        const int gcol = bn * 256 + wn * 64 + ni * 16 + r16;
        const size_t idx = (size_t)grow * N + gcol;
        float vv = acc[mi][ni][r];
        if (EP == 2) {
          ((float*)outv)[idx] = res[idx] + vv;
        } else if (EP == 3) {
          unsafeAtomicAdd((float*)outv + idx, vv);
        } else {
          if (EP == 1) { vv = fmaxf(vv, 0.0f); vv = vv * vv; }
          ((unsigned short*)outv)[idx] = f2b(vv);
        }
      }
    }
  }
}

extern "C" void kernel_launch(void* const* d_in, const int* in_sizes, int n_in,
                              void* d_out, int out_size, void* d_ws, size_t ws_size,
                              hipStream_t stream) {
  const float* x    = (const float*)d_in[0];
  const float* td   = (const float*)d_in[1];
  const float* tf   = (const float*)d_in[2];
  const float* Wk   = (const float*)d_in[3];
  const float* Wv   = (const float*)d_in[4];
  const float* Wr   = (const float*)d_in[5];
  const float* Wo   = (const float*)d_in[6];
  const float* Wffk = (const float*)d_in[7];
  const float* Wffv = (const float*)d_in[8];
  const float* g1   = (const float*)d_in[9];
  const float* b1   = (const float*)d_in[10];
  const float* g2   = (const float*)d_in[11];
  const float* b2   = (const float*)d_in[12];
  float* out = (float*)d_out;

  char* ws = (char*)d_ws;
  const size_t MB = 1024ull * 1024ull;
  unsigned short* WB    = (unsigned short*)ws;              // 24 MB contiguous bf16 weights
  unsigned short* WkvrB = WB;                               // [3072,1024]
  unsigned short* WoB   = WB + 3 * 1048576;                 // [1024,1024]
  unsigned short* WfkB  = WB + 4 * 1048576;                 // [4096,1024]
  unsigned short* WfvB  = WB + 8 * 1048576;                 // [1024,4096]
  unsigned short* xl    = (unsigned short*)(ws + 24 * MB);  // 16 MB (reused as rwkv)
  unsigned short* kvr   = (unsigned short*)(ws + 40 * MB);  // 48 MB [8192,3072] (reused as xl2)
  float*          x2    = (float*)(ws + 88 * MB);           // 32 MB
  unsigned short* hb    = (unsigned short*)(ws + 120 * MB); // 64 MB
  float*          wkvS  = (float*)(ws + 184 * MB);          // 1 MB scan scratch -> total 185 MB
  unsigned short* rwkv  = xl;   // xl dead after kvr GEMM
  unsigned short* xl2   = kvr;  // kvr dead after wkv_emit

  // weights -> bf16 + LN1 + x2:=x seed, fused single launch
  cvt_ln_kernel<<<12288 + MROWS, 256, 0, stream>>>(Wk, Wv, Wr, Wo, Wffk, Wffv, WB,
                                                   x, g1, b1, xl, x2);

  // fused k|v|r GEMM: kvr[M,3072] = xl @ WkvrB^T   (384 blocks, 256^2 tiles)
  gemm256<0><<<dim3((KVRN / 256) * (MROWS / 256), 1), 512, 0, stream>>>(
      xl, WkvrB, kvr, nullptr, KVRN, 1024, 1024);

  // WKV hierarchical scan + sigmoid(r) fuse
  wkv_local<<<64 * NCH, 64, 0, stream>>>(kvr, td, tf, wkvS);
  wkv_emit<<<64 * NCH, 64, 0, stream>>>(kvr, td, tf, wkvS, rwkv);

  // x2 += rwkv @ Wo^T  (x2 pre-seeded with x; split-K x2: 2x128 blocks, K=512 each)
  gemm256<3><<<dim3((CC / 256) * (MROWS / 256), 2), 512, 0, stream>>>(
      rwkv, WoB, x2, nullptr, CC, 1024, 512);

  // LN2 (+ seed out = x2 for the atomic split-K epilogue below)
  ln_kernel<<<MROWS, 256, 0, stream>>>(x2, g2, b2, xl2, out);

  // h = relu(xl2 @ Wffk^T)^2   (512 blocks)
  gemm256<1><<<dim3((4096 / 256) * (MROWS / 256), 1), 512, 0, stream>>>(
      xl2, WfkB, hb, nullptr, 4096, 1024, 1024);

  // out += h @ Wffv^T   (split-K x2: 2x128 blocks, K=2048 each, fp32 atomic add)
  gemm256<3><<<dim3((CC / 256) * (MROWS / 256), 2), 512, 0, stream>>>(
      hb, WfvB, out, nullptr, CC, 4096, 2048);
}